// Round 13
// baseline (154.428 us; speedup 1.0000x reference)
//
#include <hip/hip_runtime.h>

// SSIM, fused separable, v11: DUAL INDEPENDENT ROW-STREAMS PER WAVE.
// R8/R12 proved more waves never raises residency (~6 waves/CU pinned) and
// per-SIMD VALU is only ~21%: each wave stalls ~75% on its own serial
// ds_read -> H-chain -> V-chain path. This version gives each wave TWO
// independent 64-row strips (same columns, y0 and y0+64): separate rings,
// separate LDS triple pair-buffers, shared geometry. One vmcnt(8) per
// super-step covers both streams' current pairs (issued 2 super-steps back);
// both streams' compute shares a basic block so the scheduler interleaves
// the chains (B's FMAs fill A's LDS-latency bubbles). Grid 1536 x 64 thr.

#define IMG_H 512
#define IMG_W 512
#define N_PLANES 48
#define KW 11
#define BLOCK 64
#define WAVE_COLS 64
#define COLG 8                                 // 512/64 column groups
#define YPAIRS 4                               // 4 pairs of 64-row strips
#define NBLK (N_PLANES * COLG * YPAIRS)        // 1536
#define PAIRF 320           // floats per pair-buf: row0[img1 80|img2 80] row1[..]
#define C1_CONST 1.0e-4f
#define C2_CONST 9.0e-4f

typedef const __attribute__((address_space(1))) void GV;
typedef __attribute__((address_space(3))) void LV;

__device__ __forceinline__ void dma16(const float* g, float* l) {
  __builtin_amdgcn_global_load_lds((GV*)g, (LV*)l, 16, 0, 0);
}

__device__ __forceinline__ float bcastf(float x) {
  return __uint_as_float(__builtin_amdgcn_readfirstlane(__float_as_uint(x)));
}

#define TAPX(E, AV, BV) { const float w_ = Wp[(E)]; \
    const float t1_ = w_ * (AV); const float t2_ = w_ * (BV); \
    m1_ += t1_; m2_ += t2_; \
    q12_ += t1_ * (BV); qs_ += t1_ * (AV); qs_ += t2_ * (BV); }

// H-pass of one row from pair-slot base BP (img1 +0, img2 +80) into ring
// slot SLOT of ring arrays RM1..RQ12; zeros if ROW outside the image.
#define HPASS(ROW, SLOT, BP, RM1, RM2, RQS, RQ12) { \
  if ((ROW) >= 0 && (ROW) < IMG_H) { \
    const float* s1_ = (BP); const float* s2_ = (BP) + 80; \
    float m1_ = 0.f, m2_ = 0.f, qs_ = 0.f, q12_ = 0.f; \
    { const float4 A0 = *(const float4*)(s1_ + a); \
      const float4 A1 = *(const float4*)(s1_ + a + 4); \
      const float4 B0 = *(const float4*)(s2_ + a); \
      const float4 B1 = *(const float4*)(s2_ + a + 4); \
      TAPX(0, A0.x, B0.x) TAPX(1, A0.y, B0.y) TAPX(2, A0.z, B0.z) \
      TAPX(3, A0.w, B0.w) TAPX(4, A1.x, B1.x) TAPX(5, A1.y, B1.y) \
      TAPX(6, A1.z, B1.z) TAPX(7, A1.w, B1.w) } \
    { const float4 A2 = *(const float4*)(s1_ + a + 8); \
      const float2 A3 = *(const float2*)(s1_ + a + 12); \
      const float4 B2 = *(const float4*)(s2_ + a + 8); \
      const float2 B3 = *(const float2*)(s2_ + a + 12); \
      TAPX(8, A2.x, B2.x)  TAPX(9, A2.y, B2.y)  TAPX(10, A2.z, B2.z) \
      TAPX(11, A2.w, B2.w) TAPX(12, A3.x, B3.x) TAPX(13, A3.y, B3.y) } \
    RM1[(SLOT)] = m1_; RM2[(SLOT)] = m2_; \
    RQS[(SLOT)] = qs_; RQ12[(SLOT)] = q12_; \
  } else { \
    RM1[(SLOT)] = 0.f; RM2[(SLOT)] = 0.f; \
    RQS[(SLOT)] = 0.f; RQ12[(SLOT)] = 0.f; } }

#define EMT(K, QQ, RM1, RM2, RQS, RQ12) { const float w_ = wkr[(K)]; \
    vm1_ += w_ * RM1[(QQ)]; vm2_ += w_ * RM2[(QQ)]; \
    vqs_ += w_ * RQS[(QQ)]; vq12_ += w_ * RQ12[(QQ)]; }

// V-pass + SSIM for one output row; tap-k ring slot is (OFF+K)%12.
#define EMITQ(OFF, RM1, RM2, RQS, RQ12) { \
  float vm1_ = 0.f, vm2_ = 0.f, vqs_ = 0.f, vq12_ = 0.f; \
  EMT(0, ((OFF)+0)%12, RM1,RM2,RQS,RQ12)  EMT(1, ((OFF)+1)%12, RM1,RM2,RQS,RQ12) \
  EMT(2, ((OFF)+2)%12, RM1,RM2,RQS,RQ12)  EMT(3, ((OFF)+3)%12, RM1,RM2,RQS,RQ12) \
  EMT(4, ((OFF)+4)%12, RM1,RM2,RQS,RQ12)  EMT(5, ((OFF)+5)%12, RM1,RM2,RQS,RQ12) \
  EMT(6, ((OFF)+6)%12, RM1,RM2,RQS,RQ12)  EMT(7, ((OFF)+7)%12, RM1,RM2,RQS,RQ12) \
  EMT(8, ((OFF)+8)%12, RM1,RM2,RQS,RQ12)  EMT(9, ((OFF)+9)%12, RM1,RM2,RQS,RQ12) \
  EMT(10, ((OFF)+10)%12, RM1,RM2,RQS,RQ12) \
  const float mu11_ = vm1_ * vm1_; \
  const float mu22_ = vm2_ * vm2_; \
  const float mu12_ = vm1_ * vm2_; \
  const float musum_ = mu11_ + mu22_; \
  const float sigs_  = vqs_  - musum_; \
  const float sig12_ = vq12_ - mu12_; \
  const float num_ = (2.f * mu12_ + C1_CONST) * (2.f * sig12_ + C2_CONST); \
  const float den_ = (musum_ + C1_CONST) * (sigs_ + C2_CONST); \
  acc += num_ * __builtin_amdgcn_rcpf(den_); }

// One dual-stream super-step, phase P = step % 6 (compile-time).
// Issue order (matters for vmcnt): A pair, then B pair, every super-step.
// Steady state on entry: 8 outstanding (A_i,B_i,A_{i+1},B_{i+1}); issue 4
// more; vmcnt(8) retires exactly A_i+B_i (oldest 4). Both streams' H/V
// passes then share one basic block for scheduler interleaving.
#define SUPER(P, EMIT) { \
  { const int a0_ = grA+4 < 0 ? 0 : (grA+4 > IMG_H-1 ? IMG_H-1 : grA+4); \
    const int a1_ = grA+5 < 0 ? 0 : (grA+5 > IMG_H-1 ? IMG_H-1 : grA+5); \
    const int b0_ = grB+4 < 0 ? 0 : (grB+4 > IMG_H-1 ? IMG_H-1 : grB+4); \
    const int b1_ = grB+5 < 0 ? 0 : (grB+5 > IMG_H-1 ? IMG_H-1 : grB+5); \
    if (lane < 40) { \
      float* dA_ = slwA + (((P)+2)%3) * PAIRF; \
      float* dB_ = slwB + (((P)+2)%3) * PAIRF; \
      dma16(srcbase + (size_t)a0_ * IMG_W, dA_); \
      dma16(srcbase + (size_t)a1_ * IMG_W, dA_ + 160); \
      dma16(srcbase + (size_t)b0_ * IMG_W, dB_); \
      dma16(srcbase + (size_t)b1_ * IMG_W, dB_ + 160); } } \
  asm volatile("s_waitcnt vmcnt(8)" ::: "memory"); \
  __builtin_amdgcn_sched_barrier(0); \
  { const float* bpA_ = slwA + ((P)%3) * PAIRF; \
    const float* bpB_ = slwB + ((P)%3) * PAIRF; \
    HPASS(grA,     (2*(P))%12,   bpA_,       rAm1, rAm2, rAqs, rAq12) \
    HPASS(grA + 1, (2*(P)+1)%12, bpA_ + 160, rAm1, rAm2, rAqs, rAq12) \
    HPASS(grB,     (2*(P))%12,   bpB_,       rBm1, rBm2, rBqs, rBq12) \
    HPASS(grB + 1, (2*(P)+1)%12, bpB_ + 160, rBm1, rBm2, rBqs, rBq12) } \
  if (EMIT) { \
    EMITQ((2*(P)+2)%12, rAm1, rAm2, rAqs, rAq12) \
    EMITQ((2*(P)+3)%12, rAm1, rAm2, rAqs, rAq12) \
    EMITQ((2*(P)+2)%12, rBm1, rBm2, rBqs, rBq12) \
    EMITQ((2*(P)+3)%12, rBm1, rBm2, rBqs, rBq12) \
  } \
  grA += 2; grB += 2; }

__global__ __launch_bounds__(BLOCK) void ssim_strip_kernel(
    const float* __restrict__ img1,
    const float* __restrict__ img2,
    const float* __restrict__ kern2d,
    float* __restrict__ partial)
{
  // Per-stream triple pair-buffers: [stream][buf3][pair 320]. 7680 B.
  __shared__ __align__(16) float slice[2][3][PAIRF];
  __shared__ float wk_lds[KW];

  const int lane = threadIdx.x;

  // 1D kernel = row sums of the normalized 2D kernel (== normalized 1D Gaussian).
  if (lane < KW) {
    float s = 0.f;
    #pragma unroll
    for (int j = 0; j < KW; ++j) s += kern2d[lane * KW + j];
    wk_lds[lane] = s;
  }
  __syncthreads();

  // V-pass weights, wave-uniform (SGPRs).
  float wkr[KW];
  #pragma unroll
  for (int k = 0; k < KW; ++k) wkr[k] = bcastf(wk_lds[k]);

  const int bid   = blockIdx.x;
  const int plane = bid / (COLG * YPAIRS);
  const int trem  = bid % (COLG * YPAIRS);
  const int y0A   = (trem / COLG) * 128;     // stream A strip top
  const int y0B   = y0A + 64;                // stream B strip top
  const int x0w   = (trem % COLG) * WAVE_COLS;
  const float* __restrict__ p1 = img1 + (size_t)plane * IMG_H * IMG_W;
  const float* __restrict__ p2 = img2 + (size_t)plane * IMG_H * IMG_W;

  const int gx    = x0w + lane;              // this thread's output column
  const int wbase = x0w - 8;                 // slice float 0 <-> global col wbase

  // Lane's window: slice floats [a, a+13]; taps at e in [r, r+10].
  const int a = (lane + 3) & ~3;
  const int r = (lane + 3) & 3;

  float Wp[14];
  #pragma unroll
  for (int e = 0; e < 14; ++e) {
    const int k   = e - r;
    const int col = wbase + a + e;
    Wp[e] = (k >= 0 && k <= 10 && col >= 0 && col < IMG_W) ? wk_lds[k] : 0.f;
  }

  // DMA source: lanes 0..19 cover img1 floats 4l..4l+3 of the 80-float span,
  // lanes 20..39 cover img2 (landing at +80 via dest = base + lane*16).
  // Shared by both streams (same columns). Clamped groups are fully-OOB and
  // Wp-zeroed.
  const int li  = lane < 20 ? lane : lane - 20;
  const int c0r = wbase + 4 * li;
  const int c0  = c0r < 0 ? 0 : (c0r > IMG_W - 4 ? IMG_W - 4 : c0r);
  const float* srcbase = (lane < 20 ? p1 : p2) + c0;

  float* slwA = &slice[0][0][0];
  float* slwB = &slice[1][0][0];

  float rAm1[12], rAm2[12], rAqs[12], rAq12[12];
  float rBm1[12], rBm2[12], rBqs[12], rBq12[12];
  float acc = 0.f;
  int grA = y0A - 5;
  int grB = y0B - 5;

  // Prologue: pairs for super-steps 0 and 1, order A0,B0,A1,B1 (oldest first).
  {
    const int qa0 = grA   < 0 ? 0 : grA;
    const int qa1 = grA+1 < 0 ? 0 : grA+1;
    const int qa2 = grA+2 < 0 ? 0 : grA+2;
    const int qa3 = grA+3 < 0 ? 0 : grA+3;
    if (lane < 40) {
      dma16(srcbase + (size_t)qa0 * IMG_W, slwA);
      dma16(srcbase + (size_t)qa1 * IMG_W, slwA + 160);
      dma16(srcbase + (size_t)grB     * IMG_W, slwB);
      dma16(srcbase + (size_t)(grB+1) * IMG_W, slwB + 160);
      dma16(srcbase + (size_t)qa2 * IMG_W, slwA + PAIRF);
      dma16(srcbase + (size_t)qa3 * IMG_W, slwA + PAIRF + 160);
      dma16(srcbase + (size_t)(grB+2) * IMG_W, slwB + PAIRF);
      dma16(srcbase + (size_t)(grB+3) * IMG_W, slwB + PAIRF + 160);
    }
  }

  // 37 super-steps x 2 streams x 2 rows; steps 0-4 warm up, 5-36 emit.
  SUPER(0, 0) SUPER(1, 0) SUPER(2, 0) SUPER(3, 0) SUPER(4, 0)
  SUPER(5, 1)
  #pragma unroll 1
  for (int it = 0; it < 5; ++it) {
    SUPER(0, 1) SUPER(1, 1) SUPER(2, 1) SUPER(3, 1) SUPER(4, 1) SUPER(5, 1)
  }
  SUPER(0, 1)

  // Wave reduction.
  #pragma unroll
  for (int off = 32; off > 0; off >>= 1)
    acc += __shfl_down(acc, off, 64);
  if (lane == 0) partial[bid] = acc;
}

__global__ __launch_bounds__(256) void ssim_reduce_kernel(
    const float* __restrict__ partial, float* __restrict__ out)
{
  const int tid = threadIdx.x;
  double acc = 0.0;
  for (int i = tid; i < NBLK; i += 256) acc += (double)partial[i];
  #pragma unroll
  for (int off = 32; off > 0; off >>= 1)
    acc += __shfl_down(acc, off, 64);
  __shared__ double wsums[4];
  if ((tid & 63) == 0) wsums[tid >> 6] = acc;
  __syncthreads();
  if (tid == 0) {
    const double total = wsums[0] + wsums[1] + wsums[2] + wsums[3];
    const double inv_n = 1.0 / ((double)N_PLANES * IMG_H * IMG_W);
    out[0] = (float)(total * inv_n);
  }
}

extern "C" void kernel_launch(void* const* d_in, const int* in_sizes, int n_in,
                              void* d_out, int out_size, void* d_ws, size_t ws_size,
                              hipStream_t stream)
{
  const float* img1 = (const float*)d_in[0];
  const float* img2 = (const float*)d_in[1];
  const float* kern = (const float*)d_in[2];
  float* out = (float*)d_out;
  float* partial = (float*)d_ws;   // NBLK floats = 6 KiB

  ssim_strip_kernel<<<NBLK, BLOCK, 0, stream>>>(img1, img2, kern, partial);
  ssim_reduce_kernel<<<1, 256, 0, stream>>>(partial, out);
}

// Round 14
// 117.230 us; speedup vs baseline: 1.3173x; 1.3173x over previous
//
#include <hip/hip_runtime.h>

// SSIM, fused separable, v12: OVERHEAD-MINIMIZED R10.
// Theory: kernel is VALU-issue-bound with ~3-4x instruction overhead over
// useful FMAs (per-row 64-bit DMA address recompute + clamps + row guards).
// Interior strips (y0 in {64..384}, 6/8 of blocks) take a lean path: no
// clamps, no row-validity guards, one running per-lane src pointer advanced
// once per 2-row step (second row via imm offset), no gr tracking, no
// sched_barrier. Edge strips (y0=0,448) keep the R10-proven clamped path.
// Pipeline unchanged: global_load_lds pair staging (40 lanes: img1 lanes
// 0-19, img2 lanes 20-39), triple pair-buffer, counted vmcnt(4), masked
// Wp[14] windows, 4-quantity x 12-slot register ring, 6-phase unroll.

#define IMG_H 512
#define IMG_W 512
#define N_PLANES 48
#define KW 11
#define BLOCK 256
#define WAVE_COLS 64
#define STRIP_H 64
#define BLOCKS_X (IMG_W / (WAVE_COLS * 4))            // 2
#define BLOCKS_Y (IMG_H / STRIP_H)                    // 8
#define NBLK (N_PLANES * BLOCKS_X * BLOCKS_Y)         // 768
#define PAIRF 320          // floats per pair-buf: row0[img1 80|img2 80] row1[..]
#define C1_CONST 1.0e-4f
#define C2_CONST 9.0e-4f

typedef const __attribute__((address_space(1))) void GV;
typedef __attribute__((address_space(3))) void LV;

__device__ __forceinline__ void dma16(const float* g, float* l) {
  __builtin_amdgcn_global_load_lds((GV*)g, (LV*)l, 16, 0, 0);
}

__device__ __forceinline__ float bcastf(float x) {
  return __uint_as_float(__builtin_amdgcn_readfirstlane(__float_as_uint(x)));
}

#define TAPX(E, AV, BV) { const float w_ = Wp[(E)]; \
    const float t1_ = w_ * (AV); const float t2_ = w_ * (BV); \
    m1_ += t1_; m2_ += t2_; \
    q12_ += t1_ * (BV); qs_ += t1_ * (AV); qs_ += t2_ * (BV); }

// H-pass body (no row guard) from pair-slot base BP into ring slot SLOT.
#define HPASS_CORE(SLOT, BP) { \
    const float* s1_ = (BP); const float* s2_ = (BP) + 80; \
    float m1_ = 0.f, m2_ = 0.f, qs_ = 0.f, q12_ = 0.f; \
    { const float4 A0 = *(const float4*)(s1_ + a); \
      const float4 A1 = *(const float4*)(s1_ + a + 4); \
      const float4 B0 = *(const float4*)(s2_ + a); \
      const float4 B1 = *(const float4*)(s2_ + a + 4); \
      TAPX(0, A0.x, B0.x) TAPX(1, A0.y, B0.y) TAPX(2, A0.z, B0.z) \
      TAPX(3, A0.w, B0.w) TAPX(4, A1.x, B1.x) TAPX(5, A1.y, B1.y) \
      TAPX(6, A1.z, B1.z) TAPX(7, A1.w, B1.w) } \
    { const float4 A2 = *(const float4*)(s1_ + a + 8); \
      const float2 A3 = *(const float2*)(s1_ + a + 12); \
      const float4 B2 = *(const float4*)(s2_ + a + 8); \
      const float2 B3 = *(const float2*)(s2_ + a + 12); \
      TAPX(8, A2.x, B2.x)  TAPX(9, A2.y, B2.y)  TAPX(10, A2.z, B2.z) \
      TAPX(11, A2.w, B2.w) TAPX(12, A3.x, B3.x) TAPX(13, A3.y, B3.y) } \
    rm1[(SLOT)] = m1_; rm2[(SLOT)] = m2_; \
    rqs[(SLOT)] = qs_; rq12[(SLOT)] = q12_; }

// Guarded H-pass (edge path): zeros if ROW outside image.
#define HPASS_G(ROW, SLOT, BP) { \
  if ((ROW) >= 0 && (ROW) < IMG_H) { HPASS_CORE(SLOT, BP) } \
  else { rm1[(SLOT)] = 0.f; rm2[(SLOT)] = 0.f; \
         rqs[(SLOT)] = 0.f; rq12[(SLOT)] = 0.f; } }

#define EMT(K, QQ) { const float w_ = wkr[(K)]; \
    vm1_ += w_ * rm1[(QQ)]; vm2_ += w_ * rm2[(QQ)]; \
    vqs_ += w_ * rqs[(QQ)]; vq12_ += w_ * rq12[(QQ)]; }

// V-pass + SSIM for one output row whose tap-k ring slot is (OFF+K)%12.
#define EMITQ(OFF) { \
  float vm1_ = 0.f, vm2_ = 0.f, vqs_ = 0.f, vq12_ = 0.f; \
  EMT(0, ((OFF)+0)%12)  EMT(1, ((OFF)+1)%12)  EMT(2, ((OFF)+2)%12) \
  EMT(3, ((OFF)+3)%12)  EMT(4, ((OFF)+4)%12)  EMT(5, ((OFF)+5)%12) \
  EMT(6, ((OFF)+6)%12)  EMT(7, ((OFF)+7)%12)  EMT(8, ((OFF)+8)%12) \
  EMT(9, ((OFF)+9)%12)  EMT(10, ((OFF)+10)%12) \
  const float mu11_ = vm1_ * vm1_; \
  const float mu22_ = vm2_ * vm2_; \
  const float mu12_ = vm1_ * vm2_; \
  const float musum_ = mu11_ + mu22_; \
  const float sigs_  = vqs_  - musum_; \
  const float sig12_ = vq12_ - mu12_; \
  const float num_ = (2.f * mu12_ + C1_CONST) * (2.f * sig12_ + C2_CONST); \
  const float den_ = (musum_ + C1_CONST) * (sigs_ + C2_CONST); \
  acc += num_ * __builtin_amdgcn_rcpf(den_); }

// ---- INTERIOR step: no clamps, no guards, running pointer. ----
#define STEP2I(P, EMIT) { \
  if (lane < 40) { \
    float* d_ = slw + (((P)+2)%3) * PAIRF; \
    dma16(srcpf, d_); \
    dma16(srcpf + IMG_W, d_ + 160); } \
  srcpf += 2 * IMG_W; \
  asm volatile("s_waitcnt vmcnt(4)" ::: "memory"); \
  { const float* bp_ = slw + ((P)%3) * PAIRF; \
    HPASS_CORE((2*(P))%12,   bp_) \
    HPASS_CORE((2*(P)+1)%12, bp_ + 160) } \
  if (EMIT) { EMITQ((2*(P)+2)%12) EMITQ((2*(P)+3)%12) } }

// ---- EDGE step: R10 verbatim (clamped rows, guarded H-pass). ----
#define STEP2E(P, EMIT) { \
  { const int na_ = gr+4 < 0 ? 0 : (gr+4 > IMG_H-1 ? IMG_H-1 : gr+4); \
    const int nb_ = gr+5 < 0 ? 0 : (gr+5 > IMG_H-1 ? IMG_H-1 : gr+5); \
    if (lane < 40) { \
      float* d_ = slw + (((P)+2)%3) * PAIRF; \
      dma16(srcbase + (size_t)na_ * IMG_W, d_); \
      dma16(srcbase + (size_t)nb_ * IMG_W, d_ + 160); } } \
  asm volatile("s_waitcnt vmcnt(4)" ::: "memory"); \
  __builtin_amdgcn_sched_barrier(0); \
  { const float* bp_ = slw + ((P)%3) * PAIRF; \
    HPASS_G(gr,     (2*(P))%12,   bp_) \
    HPASS_G(gr + 1, (2*(P)+1)%12, bp_ + 160) } \
  if (EMIT) { EMITQ((2*(P)+2)%12) EMITQ((2*(P)+3)%12) } \
  gr += 2; }

__global__ __launch_bounds__(BLOCK) void ssim_strip_kernel(
    const float* __restrict__ img1,
    const float* __restrict__ img2,
    const float* __restrict__ kern2d,
    float* __restrict__ partial)
{
  // Wave-private triple pair-buffers: [wave][buf3][pair 320]. 15,360 B.
  __shared__ __align__(16) float slice[4][3][PAIRF];
  __shared__ float wk_lds[KW];
  __shared__ float wave_sums[BLOCK / 64];

  const int tid  = threadIdx.x;
  const int wid  = tid >> 6;
  const int lane = tid & 63;

  // 1D kernel = row sums of the normalized 2D kernel (== normalized 1D Gaussian).
  if (tid < KW) {
    float s = 0.f;
    #pragma unroll
    for (int j = 0; j < KW; ++j) s += kern2d[tid * KW + j];
    wk_lds[tid] = s;
  }
  __syncthreads();

  // V-pass weights, wave-uniform (SGPRs).
  float wkr[KW];
  #pragma unroll
  for (int k = 0; k < KW; ++k) wkr[k] = bcastf(wk_lds[k]);

  const int bid   = blockIdx.x;
  const int plane = bid / (BLOCKS_X * BLOCKS_Y);
  const int srem  = bid % (BLOCKS_X * BLOCKS_Y);
  const int y0    = (srem / BLOCKS_X) * STRIP_H;
  const int x0b   = (srem % BLOCKS_X) * (WAVE_COLS * 4);
  const float* __restrict__ p1 = img1 + (size_t)plane * IMG_H * IMG_W;
  const float* __restrict__ p2 = img2 + (size_t)plane * IMG_H * IMG_W;

  const int x0w   = x0b + wid * WAVE_COLS;   // wave's first column
  const int gx    = x0w + lane;              // this thread's output column
  const int wbase = x0w - 8;                 // slice float 0 <-> global col wbase

  // Lane's window: slice floats [a, a+13]; taps at e in [r, r+10].
  const int a = (lane + 3) & ~3;
  const int r = (lane + 3) & 3;

  float Wp[14];
  #pragma unroll
  for (int e = 0; e < 14; ++e) {
    const int k   = e - r;
    const int col = wbase + a + e;
    Wp[e] = (k >= 0 && k <= 10 && col >= 0 && col < IMG_W) ? wk_lds[k] : 0.f;
  }

  // DMA source: lanes 0..19 cover img1 floats 4l..4l+3 of the 80-float span,
  // lanes 20..39 cover img2 (landing at +80 via dest = base + lane*16).
  // wbase % 4 == 0, IMG_W % 4 == 0: each 4-float group entirely in- or
  // out-of-image; clamped addresses affect only fully-OOB groups (Wp-zeroed).
  const int li  = lane < 20 ? lane : lane - 20;
  const int c0r = wbase + 4 * li;
  const int c0  = c0r < 0 ? 0 : (c0r > IMG_W - 4 ? IMG_W - 4 : c0r);
  const float* srcbase = (lane < 20 ? p1 : p2) + c0;

  float* slw = &slice[wid][0][0];

  float rm1[12], rm2[12], rqs[12], rq12[12];
  float acc = 0.f;

  if (y0 != 0 && y0 != IMG_H - STRIP_H) {
    // ---------------- interior path (rows y0-5 .. y0+72 all valid) --------
    const float* srcrow = srcbase + (size_t)(y0 - 5) * IMG_W;
    if (lane < 40) {
      dma16(srcrow,               slw);
      dma16(srcrow + IMG_W,       slw + 160);
      dma16(srcrow + 2 * IMG_W,   slw + PAIRF);
      dma16(srcrow + 3 * IMG_W,   slw + PAIRF + 160);
    }
    const float* srcpf = srcrow + 4 * IMG_W;

    STEP2I(0, 0) STEP2I(1, 0) STEP2I(2, 0) STEP2I(3, 0) STEP2I(4, 0)
    STEP2I(5, 1)
    #pragma unroll 1
    for (int it = 0; it < 5; ++it) {
      STEP2I(0, 1) STEP2I(1, 1) STEP2I(2, 1) STEP2I(3, 1) STEP2I(4, 1) STEP2I(5, 1)
    }
    STEP2I(0, 1)
  } else {
    // ---------------- edge path (R10-proven, clamped) ---------------------
    int gr = y0 - 5;
    {
      const int q0 = gr     < 0 ? 0 : gr;
      const int q1 = gr + 1 < 0 ? 0 : gr + 1;
      const int q2 = gr + 2 < 0 ? 0 : gr + 2;
      const int q3 = gr + 3 < 0 ? 0 : gr + 3;
      if (lane < 40) {
        dma16(srcbase + (size_t)q0 * IMG_W, slw);
        dma16(srcbase + (size_t)q1 * IMG_W, slw + 160);
        dma16(srcbase + (size_t)q2 * IMG_W, slw + PAIRF);
        dma16(srcbase + (size_t)q3 * IMG_W, slw + PAIRF + 160);
      }
    }
    STEP2E(0, 0) STEP2E(1, 0) STEP2E(2, 0) STEP2E(3, 0) STEP2E(4, 0)
    STEP2E(5, 1)
    #pragma unroll 1
    for (int it = 0; it < 5; ++it) {
      STEP2E(0, 1) STEP2E(1, 1) STEP2E(2, 1) STEP2E(3, 1) STEP2E(4, 1) STEP2E(5, 1)
    }
    STEP2E(0, 1)
  }

  // Block reduction.
  #pragma unroll
  for (int off = 32; off > 0; off >>= 1)
    acc += __shfl_down(acc, off, 64);
  if ((tid & 63) == 0) wave_sums[tid >> 6] = acc;
  __syncthreads();
  if (tid == 0)
    partial[bid] = wave_sums[0] + wave_sums[1] + wave_sums[2] + wave_sums[3];
}

__global__ __launch_bounds__(256) void ssim_reduce_kernel(
    const float* __restrict__ partial, float* __restrict__ out)
{
  const int tid = threadIdx.x;
  double acc = 0.0;
  for (int i = tid; i < NBLK; i += 256) acc += (double)partial[i];
  #pragma unroll
  for (int off = 32; off > 0; off >>= 1)
    acc += __shfl_down(acc, off, 64);
  __shared__ double wsums[4];
  if ((tid & 63) == 0) wsums[tid >> 6] = acc;
  __syncthreads();
  if (tid == 0) {
    const double total = wsums[0] + wsums[1] + wsums[2] + wsums[3];
    const double inv_n = 1.0 / ((double)N_PLANES * IMG_H * IMG_W);
    out[0] = (float)(total * inv_n);
  }
}

extern "C" void kernel_launch(void* const* d_in, const int* in_sizes, int n_in,
                              void* d_out, int out_size, void* d_ws, size_t ws_size,
                              hipStream_t stream)
{
  const float* img1 = (const float*)d_in[0];
  const float* img2 = (const float*)d_in[1];
  const float* kern = (const float*)d_in[2];
  float* out = (float*)d_out;
  float* partial = (float*)d_ws;   // NBLK floats = 3 KiB

  ssim_strip_kernel<<<NBLK, BLOCK, 0, stream>>>(img1, img2, kern, partial);
  ssim_reduce_kernel<<<1, 256, 0, stream>>>(partial, out);
}

// Round 15
// 102.439 us; speedup vs baseline: 1.5075x; 1.1444x over previous
//
#include <hip/hip_runtime.h>

// SSIM, fused separable, v13 = R10 + EMIT-FIRST SOFTWARE PIPELINING.
// R10 step chain was DMA->vmcnt->ds_read->H->V: the V-pass (136 VALU) sat at
// the end of the serial chain and the vmcnt wait sat empty. Here each step
// emits output rows (gr-7, gr-6) -- which need only ring slots from PREVIOUS
// steps -- BEFORE the vmcnt wait, filling the DMA-completion window with
// useful work. HPASS then overwrites the two slots EMIT just consumed.
// Everything else identical to R10 (103.5us best): global_load_lds pair
// staging (lanes 0-19 img1, 20-39 img2), triple pair-buffer, counted
// vmcnt(4), masked Wp[14] windows, 4-quantity x 12-slot ring, 6-phase unroll.

#define IMG_H 512
#define IMG_W 512
#define N_PLANES 48
#define KW 11
#define BLOCK 256
#define WAVE_COLS 64
#define STRIP_H 64
#define BLOCKS_X (IMG_W / (WAVE_COLS * 4))            // 2
#define BLOCKS_Y (IMG_H / STRIP_H)                    // 8
#define NBLK (N_PLANES * BLOCKS_X * BLOCKS_Y)         // 768
#define PAIRF 320          // floats per pair-buf: row0[img1 80|img2 80] row1[..]
#define C1_CONST 1.0e-4f
#define C2_CONST 9.0e-4f

typedef const __attribute__((address_space(1))) void GV;
typedef __attribute__((address_space(3))) void LV;

__device__ __forceinline__ void dma16(const float* g, float* l) {
  __builtin_amdgcn_global_load_lds((GV*)g, (LV*)l, 16, 0, 0);
}

__device__ __forceinline__ float bcastf(float x) {
  return __uint_as_float(__builtin_amdgcn_readfirstlane(__float_as_uint(x)));
}

#define TAPX(E, AV, BV) { const float w_ = Wp[(E)]; \
    const float t1_ = w_ * (AV); const float t2_ = w_ * (BV); \
    m1_ += t1_; m2_ += t2_; \
    q12_ += t1_ * (BV); qs_ += t1_ * (AV); qs_ += t2_ * (BV); }

// H-pass of one row from pair-slot base BP (img1 +0, img2 +80) into ring
// slot SLOT; zeros if ROW outside the image (zero-pad convolution).
#define HPASS(ROW, SLOT, BP) { \
  if ((ROW) >= 0 && (ROW) < IMG_H) { \
    const float* s1_ = (BP); const float* s2_ = (BP) + 80; \
    float m1_ = 0.f, m2_ = 0.f, qs_ = 0.f, q12_ = 0.f; \
    { const float4 A0 = *(const float4*)(s1_ + a); \
      const float4 A1 = *(const float4*)(s1_ + a + 4); \
      const float4 B0 = *(const float4*)(s2_ + a); \
      const float4 B1 = *(const float4*)(s2_ + a + 4); \
      TAPX(0, A0.x, B0.x) TAPX(1, A0.y, B0.y) TAPX(2, A0.z, B0.z) \
      TAPX(3, A0.w, B0.w) TAPX(4, A1.x, B1.x) TAPX(5, A1.y, B1.y) \
      TAPX(6, A1.z, B1.z) TAPX(7, A1.w, B1.w) } \
    { const float4 A2 = *(const float4*)(s1_ + a + 8); \
      const float2 A3 = *(const float2*)(s1_ + a + 12); \
      const float4 B2 = *(const float4*)(s2_ + a + 8); \
      const float2 B3 = *(const float2*)(s2_ + a + 12); \
      TAPX(8, A2.x, B2.x)  TAPX(9, A2.y, B2.y)  TAPX(10, A2.z, B2.z) \
      TAPX(11, A2.w, B2.w) TAPX(12, A3.x, B3.x) TAPX(13, A3.y, B3.y) } \
    rm1[(SLOT)] = m1_; rm2[(SLOT)] = m2_; \
    rqs[(SLOT)] = qs_; rq12[(SLOT)] = q12_; \
  } else { \
    rm1[(SLOT)] = 0.f; rm2[(SLOT)] = 0.f; \
    rqs[(SLOT)] = 0.f; rq12[(SLOT)] = 0.f; } }

#define EMT(K, QQ) { const float w_ = wkr[(K)]; \
    vm1_ += w_ * rm1[(QQ)]; vm2_ += w_ * rm2[(QQ)]; \
    vqs_ += w_ * rqs[(QQ)]; vq12_ += w_ * rq12[(QQ)]; }

// V-pass + SSIM for one output row whose tap-k ring slot is (OFF+K)%12.
#define EMITQ(OFF) { \
  float vm1_ = 0.f, vm2_ = 0.f, vqs_ = 0.f, vq12_ = 0.f; \
  EMT(0, ((OFF)+0)%12)  EMT(1, ((OFF)+1)%12)  EMT(2, ((OFF)+2)%12) \
  EMT(3, ((OFF)+3)%12)  EMT(4, ((OFF)+4)%12)  EMT(5, ((OFF)+5)%12) \
  EMT(6, ((OFF)+6)%12)  EMT(7, ((OFF)+7)%12)  EMT(8, ((OFF)+8)%12) \
  EMT(9, ((OFF)+9)%12)  EMT(10, ((OFF)+10)%12) \
  const float mu11_ = vm1_ * vm1_; \
  const float mu22_ = vm2_ * vm2_; \
  const float mu12_ = vm1_ * vm2_; \
  const float musum_ = mu11_ + mu22_; \
  const float sigs_  = vqs_  - musum_; \
  const float sig12_ = vq12_ - mu12_; \
  const float num_ = (2.f * mu12_ + C1_CONST) * (2.f * sig12_ + C2_CONST); \
  const float den_ = (musum_ + C1_CONST) * (sigs_ + C2_CONST); \
  acc += num_ * __builtin_amdgcn_rcpf(den_); }

// One 2-row step, phase P = step % 6 (compile-time).
// Ring invariant at entry: slots hold H of rows gr-12..gr-1
// (slot of row x = (x - gr0) mod 12; gr - gr0 = 2*step => 2P mod 12).
// 1) issue DMA pair (gr+4, gr+5) -> buf (P+2)%3
// 2) if EMIT: output rows gr-7 (EMITQ(2P)) and gr-6 (EMITQ(2P+1)) --
//    ring-only, no dependence on this step's loads: fills the DMA wait.
// 3) vmcnt(4): pair (gr, gr+1) (issued 2 steps ago) now complete in buf P%3
// 4) HPASS rows gr, gr+1 -> slots (2P)%12, (2P+1)%12 (the slots EMIT read)
#define STEP2(P, EMIT) { \
  { const int na_ = gr+4 < 0 ? 0 : (gr+4 > IMG_H-1 ? IMG_H-1 : gr+4); \
    const int nb_ = gr+5 < 0 ? 0 : (gr+5 > IMG_H-1 ? IMG_H-1 : gr+5); \
    if (lane < 40) { \
      float* d_ = slw + (((P)+2)%3) * PAIRF; \
      dma16(srcbase + (size_t)na_ * IMG_W, d_); \
      dma16(srcbase + (size_t)nb_ * IMG_W, d_ + 160); } } \
  if (EMIT) { EMITQ((2*(P))%12) EMITQ((2*(P)+1)%12) } \
  asm volatile("s_waitcnt vmcnt(4)" ::: "memory"); \
  __builtin_amdgcn_sched_barrier(0); \
  { const float* bp_ = slw + ((P)%3) * PAIRF; \
    HPASS(gr,     (2*(P))%12,     bp_) \
    HPASS(gr + 1, (2*(P)+1)%12,   bp_ + 160) } \
  gr += 2; }

__global__ __launch_bounds__(BLOCK) void ssim_strip_kernel(
    const float* __restrict__ img1,
    const float* __restrict__ img2,
    const float* __restrict__ kern2d,
    float* __restrict__ partial)
{
  // Wave-private triple pair-buffers: [wave][buf3][pair 320]. 15,360 B.
  __shared__ __align__(16) float slice[4][3][PAIRF];
  __shared__ float wk_lds[KW];
  __shared__ float wave_sums[BLOCK / 64];

  const int tid  = threadIdx.x;
  const int wid  = tid >> 6;
  const int lane = tid & 63;

  // 1D kernel = row sums of the normalized 2D kernel (== normalized 1D Gaussian).
  if (tid < KW) {
    float s = 0.f;
    #pragma unroll
    for (int j = 0; j < KW; ++j) s += kern2d[tid * KW + j];
    wk_lds[tid] = s;
  }
  __syncthreads();

  // V-pass weights, wave-uniform (SGPRs).
  float wkr[KW];
  #pragma unroll
  for (int k = 0; k < KW; ++k) wkr[k] = bcastf(wk_lds[k]);

  const int bid   = blockIdx.x;
  const int plane = bid / (BLOCKS_X * BLOCKS_Y);
  const int srem  = bid % (BLOCKS_X * BLOCKS_Y);
  const int y0    = (srem / BLOCKS_X) * STRIP_H;
  const int x0b   = (srem % BLOCKS_X) * (WAVE_COLS * 4);
  const float* __restrict__ p1 = img1 + (size_t)plane * IMG_H * IMG_W;
  const float* __restrict__ p2 = img2 + (size_t)plane * IMG_H * IMG_W;

  const int x0w   = x0b + wid * WAVE_COLS;   // wave's first column
  const int gx    = x0w + lane;              // this thread's output column
  const int wbase = x0w - 8;                 // slice float 0 <-> global col wbase

  // Lane's window: slice floats [a, a+13]; taps at e in [r, r+10].
  const int a = (lane + 3) & ~3;
  const int r = (lane + 3) & 3;

  float Wp[14];
  #pragma unroll
  for (int e = 0; e < 14; ++e) {
    const int k   = e - r;
    const int col = wbase + a + e;
    Wp[e] = (k >= 0 && k <= 10 && col >= 0 && col < IMG_W) ? wk_lds[k] : 0.f;
  }

  // DMA source: lanes 0..19 cover img1 floats 4l..4l+3 of the 80-float span,
  // lanes 20..39 cover img2 (landing at +80 via dest = base + lane*16).
  // wbase % 4 == 0, IMG_W % 4 == 0: each 4-float group entirely in- or
  // out-of-image; clamped addresses affect only fully-OOB groups (Wp-zeroed).
  const int li  = lane < 20 ? lane : lane - 20;
  const int c0r = wbase + 4 * li;
  const int c0  = c0r < 0 ? 0 : (c0r > IMG_W - 4 ? IMG_W - 4 : c0r);
  const float* srcbase = (lane < 20 ? p1 : p2) + c0;

  float* slw = &slice[wid][0][0];

  float rm1[12], rm2[12], rqs[12], rq12[12];
  float acc = 0.f;
  int gr = y0 - 5;

  // Prologue: stage pairs for steps 0 (buf 0) and 1 (buf 1), oldest first.
  {
    const int q0 = gr     < 0 ? 0 : gr;
    const int q1 = gr + 1 < 0 ? 0 : gr + 1;
    const int q2 = gr + 2 < 0 ? 0 : gr + 2;
    const int q3 = gr + 3 < 0 ? 0 : gr + 3;
    if (lane < 40) {
      dma16(srcbase + (size_t)q0 * IMG_W, slw);
      dma16(srcbase + (size_t)q1 * IMG_W, slw + 160);
      dma16(srcbase + (size_t)q2 * IMG_W, slw + PAIRF);
      dma16(srcbase + (size_t)q3 * IMG_W, slw + PAIRF + 160);
    }
  }

  // 38 steps: s=0..5 warm the full 12-slot ring (rows y0-5..y0+6); s=6..36
  // emit rows gr-7, gr-6 before HPASS; s=37 is emit-only (rows y0+62, y0+63).
  STEP2(0, 0) STEP2(1, 0) STEP2(2, 0) STEP2(3, 0) STEP2(4, 0) STEP2(5, 0)
  #pragma unroll 1
  for (int it = 0; it < 5; ++it) {
    STEP2(0, 1) STEP2(1, 1) STEP2(2, 1) STEP2(3, 1) STEP2(4, 1) STEP2(5, 1)
  }
  STEP2(0, 1)
  // s=37 (phase 1), emit-only tail: rows y0+62, y0+63 from ring.
  { EMITQ(2) EMITQ(3) }

  // Block reduction.
  #pragma unroll
  for (int off = 32; off > 0; off >>= 1)
    acc += __shfl_down(acc, off, 64);
  if ((tid & 63) == 0) wave_sums[tid >> 6] = acc;
  __syncthreads();
  if (tid == 0)
    partial[bid] = wave_sums[0] + wave_sums[1] + wave_sums[2] + wave_sums[3];
}

__global__ __launch_bounds__(256) void ssim_reduce_kernel(
    const float* __restrict__ partial, float* __restrict__ out)
{
  const int tid = threadIdx.x;
  double acc = 0.0;
  for (int i = tid; i < NBLK; i += 256) acc += (double)partial[i];
  #pragma unroll
  for (int off = 32; off > 0; off >>= 1)
    acc += __shfl_down(acc, off, 64);
  __shared__ double wsums[4];
  if ((tid & 63) == 0) wsums[tid >> 6] = acc;
  __syncthreads();
  if (tid == 0) {
    const double total = wsums[0] + wsums[1] + wsums[2] + wsums[3];
    const double inv_n = 1.0 / ((double)N_PLANES * IMG_H * IMG_W);
    out[0] = (float)(total * inv_n);
  }
}

extern "C" void kernel_launch(void* const* d_in, const int* in_sizes, int n_in,
                              void* d_out, int out_size, void* d_ws, size_t ws_size,
                              hipStream_t stream)
{
  const float* img1 = (const float*)d_in[0];
  const float* img2 = (const float*)d_in[1];
  const float* kern = (const float*)d_in[2];
  float* out = (float*)d_out;
  float* partial = (float*)d_ws;   // NBLK floats = 3 KiB

  ssim_strip_kernel<<<NBLK, BLOCK, 0, stream>>>(img1, img2, kern, partial);
  ssim_reduce_kernel<<<1, 256, 0, stream>>>(partial, out);
}

// Round 16
// 56.839 us; speedup vs baseline: 2.7170x; 1.8023x over previous
//
#include <hip/hip_runtime.h>

// SSIM, fused separable, v14 = R15 + PACKED-FP32 (v_pk_*) H/V PASSES.
// VALUBusy 72-75% at ~1.5 resident waves/SIMD -> near VALU-issue-bound.
// CDNA VOP3P packed fp32 does 2 FMAs/instr: H-pass accumulates even/odd
// column pairs (b128 loads give aligned VGPR pairs, zero shuffle cost):
// 7 packed ops per 2 taps vs 14 scalar. V-pass rings {m1,m2},{qs,q12} as
// float2: 2 pk_fma/tap vs 4. Pipeline identical to R15: DMA pair staging,
// triple pair-buffer, counted vmcnt(4), masked Wp windows, EMIT-first.

#define IMG_H 512
#define IMG_W 512
#define N_PLANES 48
#define KW 11
#define BLOCK 256
#define WAVE_COLS 64
#define STRIP_H 64
#define BLOCKS_X (IMG_W / (WAVE_COLS * 4))            // 2
#define BLOCKS_Y (IMG_H / STRIP_H)                    // 8
#define NBLK (N_PLANES * BLOCKS_X * BLOCKS_Y)         // 768
#define PAIRF 320          // floats per pair-buf: row0[img1 80|img2 80] row1[..]
#define C1_CONST 1.0e-4f
#define C2_CONST 9.0e-4f

typedef float v2f __attribute__((ext_vector_type(2)));
typedef float v4f __attribute__((ext_vector_type(4)));

typedef const __attribute__((address_space(1))) void GV;
typedef __attribute__((address_space(3))) void LV;

__device__ __forceinline__ void dma16(const float* g, float* l) {
  __builtin_amdgcn_global_load_lds((GV*)g, (LV*)l, 16, 0, 0);
}

__device__ __forceinline__ float bcastf(float x) {
  return __uint_as_float(__builtin_amdgcn_readfirstlane(__float_as_uint(x)));
}

#define VLO(V) __builtin_shufflevector(V, V, 0, 1)
#define VHI(V) __builtin_shufflevector(V, V, 2, 3)

// One packed 2-tap group: pair weights WJ, img1 pair X1, img2 pair X2.
// 7 packed ops accumulate even/odd partial sums of all 5 quantities.
#define PTAP(WJ, X1, X2) { \
    const v2f t1_ = (WJ) * (X1); const v2f t2_ = (WJ) * (X2); \
    M1 += t1_; M2 += t2_; \
    QS += t1_ * (X1); QS += t2_ * (X2); Q12 += t1_ * (X2); }

// H-pass of one row from pair-slot base BP (img1 +0, img2 +80) into ring
// slot SLOT; zeros if ROW outside the image (zero-pad convolution).
#define HPASS(ROW, SLOT, BP) { \
  if ((ROW) >= 0 && (ROW) < IMG_H) { \
    const float* s1_ = (BP); const float* s2_ = (BP) + 80; \
    v2f M1 = {0.f,0.f}, M2 = {0.f,0.f}, QS = {0.f,0.f}, Q12 = {0.f,0.f}; \
    { const v4f A0 = *(const v4f*)(s1_ + a); \
      const v4f B0 = *(const v4f*)(s2_ + a); \
      const v4f A1 = *(const v4f*)(s1_ + a + 4); \
      const v4f B1 = *(const v4f*)(s2_ + a + 4); \
      PTAP(Wp2[0], VLO(A0), VLO(B0)) PTAP(Wp2[1], VHI(A0), VHI(B0)) \
      PTAP(Wp2[2], VLO(A1), VLO(B1)) PTAP(Wp2[3], VHI(A1), VHI(B1)) } \
    { const v4f A2 = *(const v4f*)(s1_ + a + 8); \
      const v4f B2 = *(const v4f*)(s2_ + a + 8); \
      const v2f A3 = *(const v2f*)(s1_ + a + 12); \
      const v2f B3 = *(const v2f*)(s2_ + a + 12); \
      PTAP(Wp2[4], VLO(A2), VLO(B2)) PTAP(Wp2[5], VHI(A2), VHI(B2)) \
      PTAP(Wp2[6], A3, B3) } \
    Pm[(SLOT)] = (v2f){M1.x + M1.y, M2.x + M2.y}; \
    Pq[(SLOT)] = (v2f){QS.x + QS.y, Q12.x + Q12.y}; \
  } else { \
    Pm[(SLOT)] = (v2f){0.f, 0.f}; Pq[(SLOT)] = (v2f){0.f, 0.f}; } }

#define EMT(K, QQ) { const float w_ = wkr[(K)]; \
    vmP += w_ * Pm[(QQ)]; vqP += w_ * Pq[(QQ)]; }

// V-pass + SSIM for one output row whose tap-k ring slot is (OFF+K)%12.
#define EMITQ(OFF) { \
  v2f vmP = {0.f,0.f}, vqP = {0.f,0.f}; \
  EMT(0, ((OFF)+0)%12)  EMT(1, ((OFF)+1)%12)  EMT(2, ((OFF)+2)%12) \
  EMT(3, ((OFF)+3)%12)  EMT(4, ((OFF)+4)%12)  EMT(5, ((OFF)+5)%12) \
  EMT(6, ((OFF)+6)%12)  EMT(7, ((OFF)+7)%12)  EMT(8, ((OFF)+8)%12) \
  EMT(9, ((OFF)+9)%12)  EMT(10, ((OFF)+10)%12) \
  const float vm1_ = vmP.x, vm2_ = vmP.y, vqs_ = vqP.x, vq12_ = vqP.y; \
  const float mu11_ = vm1_ * vm1_; \
  const float mu22_ = vm2_ * vm2_; \
  const float mu12_ = vm1_ * vm2_; \
  const float musum_ = mu11_ + mu22_; \
  const float sigs_  = vqs_  - musum_; \
  const float sig12_ = vq12_ - mu12_; \
  const float num_ = (2.f * mu12_ + C1_CONST) * (2.f * sig12_ + C2_CONST); \
  const float den_ = (musum_ + C1_CONST) * (sigs_ + C2_CONST); \
  acc += num_ * __builtin_amdgcn_rcpf(den_); }

// One 2-row step, phase P = step % 6 (compile-time). EMIT-first (R15):
// 1) issue DMA pair (gr+4, gr+5) -> buf (P+2)%3
// 2) if EMIT: output rows gr-7, gr-6 (ring-only; fills the DMA wait)
// 3) vmcnt(4): pair (gr, gr+1) (issued 2 steps ago) complete in buf P%3
// 4) HPASS rows gr, gr+1 -> slots (2P)%12, (2P+1)%12
#define STEP2(P, EMIT) { \
  { const int na_ = gr+4 < 0 ? 0 : (gr+4 > IMG_H-1 ? IMG_H-1 : gr+4); \
    const int nb_ = gr+5 < 0 ? 0 : (gr+5 > IMG_H-1 ? IMG_H-1 : gr+5); \
    if (lane < 40) { \
      float* d_ = slw + (((P)+2)%3) * PAIRF; \
      dma16(srcbase + (size_t)na_ * IMG_W, d_); \
      dma16(srcbase + (size_t)nb_ * IMG_W, d_ + 160); } } \
  if (EMIT) { EMITQ((2*(P))%12) EMITQ((2*(P)+1)%12) } \
  asm volatile("s_waitcnt vmcnt(4)" ::: "memory"); \
  __builtin_amdgcn_sched_barrier(0); \
  { const float* bp_ = slw + ((P)%3) * PAIRF; \
    HPASS(gr,     (2*(P))%12,     bp_) \
    HPASS(gr + 1, (2*(P)+1)%12,   bp_ + 160) } \
  gr += 2; }

__global__ __launch_bounds__(BLOCK) void ssim_strip_kernel(
    const float* __restrict__ img1,
    const float* __restrict__ img2,
    const float* __restrict__ kern2d,
    float* __restrict__ partial)
{
  // Wave-private triple pair-buffers: [wave][buf3][pair 320]. 15,360 B.
  __shared__ __align__(16) float slice[4][3][PAIRF];
  __shared__ float wk_lds[KW];
  __shared__ float wave_sums[BLOCK / 64];

  const int tid  = threadIdx.x;
  const int wid  = tid >> 6;
  const int lane = tid & 63;

  // 1D kernel = row sums of the normalized 2D kernel (== normalized 1D Gaussian).
  if (tid < KW) {
    float s = 0.f;
    #pragma unroll
    for (int j = 0; j < KW; ++j) s += kern2d[tid * KW + j];
    wk_lds[tid] = s;
  }
  __syncthreads();

  // V-pass weights, wave-uniform (SGPRs).
  float wkr[KW];
  #pragma unroll
  for (int k = 0; k < KW; ++k) wkr[k] = bcastf(wk_lds[k]);

  const int bid   = blockIdx.x;
  const int plane = bid / (BLOCKS_X * BLOCKS_Y);
  const int srem  = bid % (BLOCKS_X * BLOCKS_Y);
  const int y0    = (srem / BLOCKS_X) * STRIP_H;
  const int x0b   = (srem % BLOCKS_X) * (WAVE_COLS * 4);
  const float* __restrict__ p1 = img1 + (size_t)plane * IMG_H * IMG_W;
  const float* __restrict__ p2 = img2 + (size_t)plane * IMG_H * IMG_W;

  const int x0w   = x0b + wid * WAVE_COLS;   // wave's first column
  const int gx    = x0w + lane;              // this thread's output column
  const int wbase = x0w - 8;                 // slice float 0 <-> global col wbase

  // Lane's window: slice floats [a, a+13]; taps at e in [r, r+10].
  const int a = (lane + 3) & ~3;
  const int r = (lane + 3) & 3;

  // Per-lane masked weights over the 14-float span, packed as 7 pairs.
  v2f Wp2[7];
  #pragma unroll
  for (int j = 0; j < 7; ++j) {
    float w0, w1;
    {
      const int e = 2 * j;
      const int k = e - r;
      const int col = wbase + a + e;
      w0 = (k >= 0 && k <= 10 && col >= 0 && col < IMG_W) ? wk_lds[k] : 0.f;
    }
    {
      const int e = 2 * j + 1;
      const int k = e - r;
      const int col = wbase + a + e;
      w1 = (k >= 0 && k <= 10 && col >= 0 && col < IMG_W) ? wk_lds[k] : 0.f;
    }
    Wp2[j] = (v2f){w0, w1};
  }

  // DMA source: lanes 0..19 cover img1 floats 4l..4l+3 of the 80-float span,
  // lanes 20..39 cover img2 (landing at +80 via dest = base + lane*16).
  // wbase % 4 == 0, IMG_W % 4 == 0: each 4-float group entirely in- or
  // out-of-image; clamped addresses affect only fully-OOB groups (Wp-zeroed).
  const int li  = lane < 20 ? lane : lane - 20;
  const int c0r = wbase + 4 * li;
  const int c0  = c0r < 0 ? 0 : (c0r > IMG_W - 4 ? IMG_W - 4 : c0r);
  const float* srcbase = (lane < 20 ? p1 : p2) + c0;

  float* slw = &slice[wid][0][0];

  v2f Pm[12], Pq[12];   // ring: {m1,m2}, {qs,q12} per slot (48 VGPR)
  float acc = 0.f;
  int gr = y0 - 5;

  // Prologue: stage pairs for steps 0 (buf 0) and 1 (buf 1), oldest first.
  {
    const int q0 = gr     < 0 ? 0 : gr;
    const int q1 = gr + 1 < 0 ? 0 : gr + 1;
    const int q2 = gr + 2 < 0 ? 0 : gr + 2;
    const int q3 = gr + 3 < 0 ? 0 : gr + 3;
    if (lane < 40) {
      dma16(srcbase + (size_t)q0 * IMG_W, slw);
      dma16(srcbase + (size_t)q1 * IMG_W, slw + 160);
      dma16(srcbase + (size_t)q2 * IMG_W, slw + PAIRF);
      dma16(srcbase + (size_t)q3 * IMG_W, slw + PAIRF + 160);
    }
  }

  // 38 steps: s=0..5 warm the 12-slot ring; s=6..36 emit rows gr-7, gr-6
  // before HPASS; tail emits rows y0+62, y0+63 (phase 1, emit-only).
  STEP2(0, 0) STEP2(1, 0) STEP2(2, 0) STEP2(3, 0) STEP2(4, 0) STEP2(5, 0)
  #pragma unroll 1
  for (int it = 0; it < 5; ++it) {
    STEP2(0, 1) STEP2(1, 1) STEP2(2, 1) STEP2(3, 1) STEP2(4, 1) STEP2(5, 1)
  }
  STEP2(0, 1)
  { EMITQ(2) EMITQ(3) }

  // Block reduction.
  #pragma unroll
  for (int off = 32; off > 0; off >>= 1)
    acc += __shfl_down(acc, off, 64);
  if ((tid & 63) == 0) wave_sums[tid >> 6] = acc;
  __syncthreads();
  if (tid == 0)
    partial[bid] = wave_sums[0] + wave_sums[1] + wave_sums[2] + wave_sums[3];
}

__global__ __launch_bounds__(256) void ssim_reduce_kernel(
    const float* __restrict__ partial, float* __restrict__ out)
{
  const int tid = threadIdx.x;
  double acc = 0.0;
  for (int i = tid; i < NBLK; i += 256) acc += (double)partial[i];
  #pragma unroll
  for (int off = 32; off > 0; off >>= 1)
    acc += __shfl_down(acc, off, 64);
  __shared__ double wsums[4];
  if ((tid & 63) == 0) wsums[tid >> 6] = acc;
  __syncthreads();
  if (tid == 0) {
    const double total = wsums[0] + wsums[1] + wsums[2] + wsums[3];
    const double inv_n = 1.0 / ((double)N_PLANES * IMG_H * IMG_W);
    out[0] = (float)(total * inv_n);
  }
}

extern "C" void kernel_launch(void* const* d_in, const int* in_sizes, int n_in,
                              void* d_out, int out_size, void* d_ws, size_t ws_size,
                              hipStream_t stream)
{
  const float* img1 = (const float*)d_in[0];
  const float* img2 = (const float*)d_in[1];
  const float* kern = (const float*)d_in[2];
  float* out = (float*)d_out;
  float* partial = (float*)d_ws;   // NBLK floats = 3 KiB

  ssim_strip_kernel<<<NBLK, BLOCK, 0, stream>>>(img1, img2, kern, partial);
  ssim_reduce_kernel<<<1, 256, 0, stream>>>(partial, out);
}